// Round 11
// baseline (2795.924 us; speedup 1.0000x reference)
//
#include <hip/hip_runtime.h>
#include <hip/hip_fp16.h>

#define N_NODES 65536
#define N_EDGES 1048576
#define N_LABEL 2097152
#define DIM_IN 32
#define DIM_H 64

// ---------------- CSR build + norm precompute ----------------

__global__ void k_init(float* __restrict__ deg, int* __restrict__ cnt) {
    int v = blockIdx.x * blockDim.x + threadIdx.x;
    deg[v] = 1.0f;  // self-loop weight
    cnt[v] = 0;
}

__global__ void k_cnt(const int* __restrict__ ei, const float* __restrict__ w,
                      int* __restrict__ cnt, float* __restrict__ deg) {
    int e = blockIdx.x * blockDim.x + threadIdx.x;
    int d = ei[N_EDGES + e];
    atomicAdd(&cnt[d], 1);
    atomicAdd(&deg[d], w[e]);
}

// hierarchical exclusive scan over cnt[N] (64 blocks x 1024)
__global__ void k_scan1(const int* __restrict__ cnt, int* __restrict__ blksum) {
    int tid = threadIdx.x;
    const int4* p = (const int4*)(cnt + blockIdx.x * 1024);
    int4 v = p[tid];
    int s = v.x + v.y + v.z + v.w;
    for (int d = 1; d < 64; d <<= 1) s += __shfl_xor(s, d);
    __shared__ int wsum[4];
    if ((tid & 63) == 0) wsum[tid >> 6] = s;
    __syncthreads();
    if (tid == 0) blksum[blockIdx.x] = wsum[0] + wsum[1] + wsum[2] + wsum[3];
}

__global__ void k_scan2(int* __restrict__ blksum) {
    if (threadIdx.x == 0) {
        int run = 0;
        for (int i = 0; i < 64; ++i) { int t = blksum[i]; blksum[i] = run; run += t; }
    }
}

__global__ void k_scan3(const int* __restrict__ cnt, const int* __restrict__ blksum,
                        int* __restrict__ offs, int* __restrict__ cursor) {
    int tid = threadIdx.x, bid = blockIdx.x;
    const int4* p = (const int4*)(cnt + bid * 1024);
    int4 v = p[tid];
    int s = v.x + v.y + v.z + v.w;
    int lane = tid & 63, wid = tid >> 6;
    int sc = s;
    for (int d = 1; d < 64; d <<= 1) {
        int t = __shfl_up(sc, d);
        if (lane >= d) sc += t;
    }
    __shared__ int wsum[4];
    if (lane == 63) wsum[wid] = sc;
    __syncthreads();
    int base = blksum[bid];
    for (int w2 = 0; w2 < wid; ++w2) base += wsum[w2];
    int ex = base + sc - s;  // exclusive prefix of this thread's 4 entries
    int idx = bid * 1024 + tid * 4;
    int o0 = ex, o1 = o0 + v.x, o2 = o1 + v.y, o3 = o2 + v.z;
    offs[idx] = o0; offs[idx + 1] = o1; offs[idx + 2] = o2; offs[idx + 3] = o3;
    cursor[idx] = o0; cursor[idx + 1] = o1; cursor[idx + 2] = o2; cursor[idx + 3] = o3;
    if (bid == 63 && tid == 255) offs[N_NODES] = o3 + v.w;  // == N_EDGES
}

__global__ void k_dinv(float* __restrict__ deg) {
    int v = blockIdx.x * blockDim.x + threadIdx.x;
    deg[v] = rsqrtf(deg[v]);
}

// packed CSR entry: {src | (dst&31)<<16, norm-as-bits}; src < 65536 fits 16 bits,
// and blocks own 32-aligned dst ranges so dst&31 is the block-local row.
__global__ void k_fill(const int* __restrict__ ei, const float* __restrict__ w,
                       const float* __restrict__ dinv, int* __restrict__ cursor,
                       int2* __restrict__ csr_se) {
    int e = blockIdx.x * blockDim.x + threadIdx.x;
    int s = ei[e];
    int d = ei[N_EDGES + e];
    int pos = atomicAdd(&cursor[d], 1);
    float nm = dinv[s] * w[e] * dinv[d];
    csr_se[pos] = make_int2(s | ((d & 31) << 16), __float_as_int(nm));
}

// ---------------- cast x to fp16 ----------------

__global__ void k_cast_x(const float* __restrict__ x, __half* __restrict__ xh) {
    int gid = blockIdx.x * 256 + threadIdx.x;  // N*32 threads
    xh[gid] = __float2half(x[gid]);
}

// ---------------- edge-parallel fused layer ----------------
// Block owns nodes [32b, 32b+32) and their contiguous CSR edge range.
// Gather phase: each LPE-lane group handles one edge unconditionally
// (lane = one uint4 = 8 halves of the row), scales, accumulates into a
// padded fp32 LDS table via ds_add (order-independent sums, no windows,
// no dependent metadata round -> decode-like flat gather stream).
// Epilogue: self-loop + shfl-GEMM transform + bias/ReLU per node.

template <int K, bool RELU>
__global__ void __launch_bounds__(256) k_layer_ep(
        const int* __restrict__ offs, const int2* __restrict__ csr_se,
        const __half* __restrict__ h, const float* __restrict__ dinv,
        const float* __restrict__ W, const float* __restrict__ b,
        __half* __restrict__ out) {
    constexpr int LPE = K / 8;     // lanes per edge (uint4 each): 4 (K=32) or 8 (K=64)
    constexpr int EPB = 256 / LPE; // edges per block-iteration: 64 or 32
    constexpr int S   = K + 2;     // padded LDS row stride (floats)

    __shared__ float acc[32 * S];
    __shared__ float Wl[K * 64];

    int tid = threadIdx.x;
    for (int i = tid; i < K * 64; i += 256) Wl[i] = W[i];
    for (int i = tid; i < 32 * S; i += 256) acc[i] = 0.f;
    __syncthreads();

    int v0 = blockIdx.x * 32;
    int j0 = __builtin_amdgcn_readfirstlane(offs[v0]);
    int j1 = __builtin_amdgcn_readfirstlane(offs[v0 + 32]);

    int g   = tid / LPE;   // edge slot within the block-iteration
    int sub = tid % LPE;   // 16 B chunk of the row

    for (int jb = j0; jb < j1; jb += EPB) {
        int e  = jb + g;
        int ec = e < j1 ? e : j0;                 // clamped (loop entered => j1 > j0)
        int2 se = csr_se[ec];                     // coalesced streaming metadata
        float nm = (e < j1) ? __int_as_float(se.y) : 0.f;
        int src = se.x & 0xFFFF;
        int row = (se.x >> 16) & 31;
        uint4 rv = *(const uint4*)(h + (size_t)src * K + sub * 8);
        const __half2* hp = (const __half2*)&rv;
        float* dstp = &acc[row * S + sub * 8];
#pragma unroll
        for (int i = 0; i < 4; ++i) {
            float2 f = __half22float2(hp[i]);
            atomicAdd(dstp + 2 * i,     nm * f.x);
            atomicAdd(dstp + 2 * i + 1, nm * f.y);
        }
    }
    __syncthreads();

    // epilogue: 4 waves x 8 nodes
    int wave = tid >> 6, lane = tid & 63;
    int k = lane & (K - 1);
#pragma unroll
    for (int n = 0; n < 8; ++n) {
        int v = v0 + wave * 8 + n;
        float a = acc[(v & 31) * S + k];
        float dv = dinv[v];
        a += dv * dv * __half2float(h[(size_t)v * K + k]);  // self-loop
        float o0 = 0.f, o1 = 0.f, o2 = 0.f, o3 = 0.f;
#pragma unroll
        for (int kk = 0; kk < K; kk += 4) {
            o0 += __shfl(a, kk + 0) * Wl[(kk + 0) * 64 + lane];
            o1 += __shfl(a, kk + 1) * Wl[(kk + 1) * 64 + lane];
            o2 += __shfl(a, kk + 2) * Wl[(kk + 2) * 64 + lane];
            o3 += __shfl(a, kk + 3) * Wl[(kk + 3) * 64 + lane];
        }
        float o = (o0 + o1) + (o2 + o3) + b[lane];
        if (RELU) o = fmaxf(o, 0.f);
        out[(size_t)v * 64 + lane] = __float2half(o);
    }
}

// ---------------- decode: out[p] = dot(enc[a], enc[b]); 8 lanes/pair, fp16 rows ----------------

__device__ __forceinline__ float dot8h(uint4 ua, uint4 ub) {
    const __half2* pa = (const __half2*)&ua;
    const __half2* pb = (const __half2*)&ub;
    float s = 0.f;
#pragma unroll
    for (int i = 0; i < 4; ++i) {
        float2 fa = __half22float2(pa[i]);
        float2 fb = __half22float2(pb[i]);
        s += fa.x * fb.x + fa.y * fb.y;
    }
    return s;
}

__global__ void __launch_bounds__(256) k_decode(
        const int* __restrict__ eli, const __half* __restrict__ enc,
        float* __restrict__ out) {
    int gid = blockIdx.x * 256 + threadIdx.x;  // EL*8 threads
    int p = gid >> 3;
    int c8 = gid & 7;  // 8 halves (16 B) per lane
    int a = eli[p];
    int b = eli[N_LABEL + p];
    uint4 ua = *(const uint4*)(enc + (size_t)a * 64 + c8 * 8);
    uint4 ub = *(const uint4*)(enc + (size_t)b * 64 + c8 * 8);
    float s = dot8h(ua, ub);
    s += __shfl_xor(s, 1, 8);
    s += __shfl_xor(s, 2, 8);
    s += __shfl_xor(s, 4, 8);
    if (c8 == 0) out[p] = s;
}

// ---------------- host ----------------

extern "C" void kernel_launch(void* const* d_in, const int* in_sizes, int n_in,
                              void* d_out, int out_size, void* d_ws, size_t ws_size,
                              hipStream_t stream) {
    const float* x   = (const float*)d_in[0];
    const int*   ei  = (const int*)d_in[1];
    const float* ew  = (const float*)d_in[2];
    const int*   eli = (const int*)d_in[3];
    const float* W[6] = {(const float*)d_in[4],  (const float*)d_in[6],
                         (const float*)d_in[8],  (const float*)d_in[10],
                         (const float*)d_in[12], (const float*)d_in[14]};
    const float* B[6] = {(const float*)d_in[5],  (const float*)d_in[7],
                         (const float*)d_in[9],  (const float*)d_in[11],
                         (const float*)d_in[13], (const float*)d_in[15]};

    char* ws = (char*)d_ws;
    float*  dinv    = (float*)ws;   ws += N_NODES * 4;
    int*    cnt     = (int*)ws;     ws += N_NODES * 4;
    int*    offs    = (int*)ws;     ws += (N_NODES + 16) * 4;
    int*    cursor  = (int*)ws;     ws += N_NODES * 4;
    int*    blksum  = (int*)ws;     ws += 256 * 4;
    int2*   csr_se  = (int2*)ws;    ws += (size_t)N_EDGES * 8;
    __half* xh      = (__half*)ws;  ws += (size_t)N_NODES * DIM_IN * 2;
    __half* hA      = (__half*)ws;  ws += (size_t)N_NODES * 64 * 2;
    __half* hB      = (__half*)ws;

    const int BS = 256;
    const int gEP = N_NODES / 32;  // 2048 blocks, 32 nodes each

    // CSR build + norm
    k_init <<<N_NODES / BS, BS, 0, stream>>>(dinv, cnt);
    k_cnt  <<<N_EDGES / BS, BS, 0, stream>>>(ei, ew, cnt, dinv);
    k_scan1<<<64, BS, 0, stream>>>(cnt, blksum);
    k_scan2<<<1, 64, 0, stream>>>(blksum);
    k_scan3<<<64, BS, 0, stream>>>(cnt, blksum, offs, cursor);
    k_dinv <<<N_NODES / BS, BS, 0, stream>>>(dinv);
    k_fill <<<N_EDGES / BS, BS, 0, stream>>>(ei, ew, dinv, cursor, csr_se);

    // cast x to fp16
    k_cast_x<<<N_NODES * DIM_IN / BS, BS, 0, stream>>>(x, xh);

    // edge-parallel fused layers (fp16 tables, fp32 accumulation)
    k_layer_ep<DIM_IN, true ><<<gEP, BS, 0, stream>>>(offs, csr_se, xh, dinv, W[0], B[0], hA);
    k_layer_ep<DIM_H,  true ><<<gEP, BS, 0, stream>>>(offs, csr_se, hA, dinv, W[1], B[1], hB);
    k_layer_ep<DIM_H,  true ><<<gEP, BS, 0, stream>>>(offs, csr_se, hB, dinv, W[2], B[2], hA);
    k_layer_ep<DIM_H,  true ><<<gEP, BS, 0, stream>>>(offs, csr_se, hA, dinv, W[3], B[3], hB);
    k_layer_ep<DIM_H,  true ><<<gEP, BS, 0, stream>>>(offs, csr_se, hB, dinv, W[4], B[4], hA);
    k_layer_ep<DIM_H, false><<<gEP, BS, 0, stream>>>(offs, csr_se, hA, dinv, W[5], B[5], hB);

    // decode (8 lanes per pair)
    k_decode<<<N_LABEL * 8 / BS, BS, 0, stream>>>(eli, hB, (float*)d_out);
}

// Round 13
// 764.277 us; speedup vs baseline: 3.6583x; 3.6583x over previous
//
#include <hip/hip_runtime.h>
#include <hip/hip_fp16.h>

#define N_NODES 65536
#define N_EDGES 1048576
#define N_LABEL 2097152
#define DIM_IN 32
#define DIM_H 64

// ---------------- CSR build + norm precompute ----------------

__global__ void k_init(float* __restrict__ deg, int* __restrict__ cnt) {
    int v = blockIdx.x * blockDim.x + threadIdx.x;
    deg[v] = 1.0f;  // self-loop weight
    cnt[v] = 0;
}

__global__ void k_cnt(const int* __restrict__ ei, const float* __restrict__ w,
                      int* __restrict__ cnt, float* __restrict__ deg) {
    int e = blockIdx.x * blockDim.x + threadIdx.x;
    int d = ei[N_EDGES + e];
    atomicAdd(&cnt[d], 1);
    atomicAdd(&deg[d], w[e]);
}

// hierarchical exclusive scan over cnt[N] (64 blocks x 1024)
__global__ void k_scan1(const int* __restrict__ cnt, int* __restrict__ blksum) {
    int tid = threadIdx.x;
    const int4* p = (const int4*)(cnt + blockIdx.x * 1024);
    int4 v = p[tid];
    int s = v.x + v.y + v.z + v.w;
    for (int d = 1; d < 64; d <<= 1) s += __shfl_xor(s, d);
    __shared__ int wsum[4];
    if ((tid & 63) == 0) wsum[tid >> 6] = s;
    __syncthreads();
    if (tid == 0) blksum[blockIdx.x] = wsum[0] + wsum[1] + wsum[2] + wsum[3];
}

__global__ void k_scan2(int* __restrict__ blksum) {
    if (threadIdx.x == 0) {
        int run = 0;
        for (int i = 0; i < 64; ++i) { int t = blksum[i]; blksum[i] = run; run += t; }
    }
}

__global__ void k_scan3(const int* __restrict__ cnt, const int* __restrict__ blksum,
                        int* __restrict__ offs, int* __restrict__ cursor) {
    int tid = threadIdx.x, bid = blockIdx.x;
    const int4* p = (const int4*)(cnt + bid * 1024);
    int4 v = p[tid];
    int s = v.x + v.y + v.z + v.w;
    int lane = tid & 63, wid = tid >> 6;
    int sc = s;
    for (int d = 1; d < 64; d <<= 1) {
        int t = __shfl_up(sc, d);
        if (lane >= d) sc += t;
    }
    __shared__ int wsum[4];
    if (lane == 63) wsum[wid] = sc;
    __syncthreads();
    int base = blksum[bid];
    for (int w2 = 0; w2 < wid; ++w2) base += wsum[w2];
    int ex = base + sc - s;  // exclusive prefix of this thread's 4 entries
    int idx = bid * 1024 + tid * 4;
    int o0 = ex, o1 = o0 + v.x, o2 = o1 + v.y, o3 = o2 + v.z;
    offs[idx] = o0; offs[idx + 1] = o1; offs[idx + 2] = o2; offs[idx + 3] = o3;
    cursor[idx] = o0; cursor[idx + 1] = o1; cursor[idx + 2] = o2; cursor[idx + 3] = o3;
    if (bid == 63 && tid == 255) offs[N_NODES] = o3 + v.w;  // == N_EDGES
}

__global__ void k_dinv(float* __restrict__ deg) {
    int v = blockIdx.x * blockDim.x + threadIdx.x;
    deg[v] = rsqrtf(deg[v]);
}

// packed CSR entry: {src, norm-as-bits}
__global__ void k_fill(const int* __restrict__ ei, const float* __restrict__ w,
                       const float* __restrict__ dinv, int* __restrict__ cursor,
                       int2* __restrict__ csr_se) {
    int e = blockIdx.x * blockDim.x + threadIdx.x;
    int s = ei[e];
    int d = ei[N_EDGES + e];
    int pos = atomicAdd(&cursor[d], 1);
    float nm = dinv[s] * w[e] * dinv[d];
    csr_se[pos] = make_int2(s, __float_as_int(nm));
}

// ---------------- cast x to fp16 ----------------

__global__ void k_cast_x(const float* __restrict__ x, __half* __restrict__ xh) {
    int gid = blockIdx.x * 256 + threadIdx.x;  // N*32 threads
    xh[gid] = __float2half(x[gid]);
}

// ---------------- fused layer: out[v] = half( relu( (Ah)[v] @ W + b ) ) ----------------
// One 64-lane wave per node. Lane split: sub = lane%LPE picks a 16 B (uint4 = 8
// halves) chunk of the edge row, g = lane/LPE picks the edge slot -> ONE gather
// instruction covers EPI = 64/LPE edge rows (8 for K=64, 16 for K=32).
// Metadata for up to 64 edges is loaded ONCE per node (coalesced int2/lane);
// out-of-range slots get md.y (norm) zeroed AT LOAD TIME so every __shfl below
// runs with all 64 lanes active (round-12 bug: divergent bpermute from inactive
// lanes is undefined). Tail edges thus contribute exactly 0 via nm=0 with a
// valid clamped address. 8 fp32 partial accumulators per lane; xor-tree reduce;
// shfl-GEMM transform.

template <int K, bool RELU>
__global__ void __launch_bounds__(256) k_layer(
        const int* __restrict__ offs, const int2* __restrict__ csr_se,
        const __half* __restrict__ h, const float* __restrict__ dinv,
        const float* __restrict__ W, const float* __restrict__ b,
        __half* __restrict__ out) {
    __shared__ float Wl[K * 64];
    int tid = threadIdx.x;
    for (int i = tid; i < K * 64; i += 256) Wl[i] = W[i];
    __syncthreads();

    constexpr int LPE = K / 8;     // lanes per edge row (uint4 each): 4 or 8
    constexpr int EPI = 64 / LPE;  // edges per gather instruction: 16 or 8

    int v = blockIdx.x * 4 + (tid >> 6);
    int lane = tid & 63;
    int sub = lane % LPE;          // 16 B chunk of row
    int g   = lane / LPE;          // edge slot

    float a[8] = {0.f, 0.f, 0.f, 0.f, 0.f, 0.f, 0.f, 0.f};

    // self-loop term (edge-slot 0 lanes only; no cross-lane ops inside)
    if (g == 0) {
        float dv = dinv[v];
        float sl = dv * dv;
        uint4 rv = *(const uint4*)(h + (size_t)v * K + sub * 8);
        const __half2* hp = (const __half2*)&rv;
#pragma unroll
        for (int i = 0; i < 4; ++i) {
            float2 f = __half22float2(hp[i]);
            a[2 * i]     += sl * f.x;
            a[2 * i + 1] += sl * f.y;
        }
    }

    int j0 = __builtin_amdgcn_readfirstlane(offs[v]);
    int j1 = __builtin_amdgcn_readfirstlane(offs[v + 1]);

    for (int jm = j0; jm < j1; jm += 64) {
        // metadata for up to 64 edges: one coalesced int2 load per lane;
        // out-of-range slots -> clamped valid address, norm zeroed (cndmask,
        // not a branch) so downstream shfls are fully convergent.
        int mi = jm + lane;
        int2 md = csr_se[mi < j1 ? mi : j1 - 1];   // loop entered => j1 > j0
        if (mi >= j1) md.y = 0;                    // 0.0f bit pattern
        int nwin = j1 - jm;
        if (nwin > 64) nwin = 64;
        for (int t = 0; t * EPI < nwin; ++t) {     // wave-uniform trip count
            int we = t * EPI + g;                  // window slot (< 64)
            int src = __shfl(md.x, we);            // all 64 lanes active
            float nm = __int_as_float(__shfl(md.y, we));
            uint4 rv = *(const uint4*)(h + (size_t)src * K + sub * 8);
            const __half2* hp = (const __half2*)&rv;
#pragma unroll
            for (int i = 0; i < 4; ++i) {
                float2 f = __half22float2(hp[i]);
                a[2 * i]     += nm * f.x;
                a[2 * i + 1] += nm * f.y;
            }
        }
    }

    // xor-tree: sum partials across edge slots (group bits log2(LPE)..5)
#pragma unroll
    for (int st = LPE; st < 64; st <<= 1) {
#pragma unroll
        for (int i = 0; i < 8; ++i) a[i] += __shfl_xor(a[i], st);
    }

    // transform: o[lane] = sum_k agg[k] * W[k][lane] + b[lane]
    // agg[k] lives at lane (k>>3) (sub == k>>3 there), element k&7.
    float o = b[lane];
#pragma unroll
    for (int k = 0; k < K; ++k) {
        o += __shfl(a[k & 7], k >> 3) * Wl[k * 64 + lane];
    }
    if (RELU) o = fmaxf(o, 0.f);
    out[(size_t)v * 64 + lane] = __float2half(o);
}

// ---------------- decode: out[p] = dot(enc[a], enc[b]); 8 lanes/pair, fp16 rows ----------------

__device__ __forceinline__ float dot8h(uint4 ua, uint4 ub) {
    const __half2* pa = (const __half2*)&ua;
    const __half2* pb = (const __half2*)&ub;
    float s = 0.f;
#pragma unroll
    for (int i = 0; i < 4; ++i) {
        float2 fa = __half22float2(pa[i]);
        float2 fb = __half22float2(pb[i]);
        s += fa.x * fb.x + fa.y * fb.y;
    }
    return s;
}

__global__ void __launch_bounds__(256) k_decode(
        const int* __restrict__ eli, const __half* __restrict__ enc,
        float* __restrict__ out) {
    int gid = blockIdx.x * 256 + threadIdx.x;  // EL*8 threads
    int p = gid >> 3;
    int c8 = gid & 7;  // 8 halves (16 B) per lane
    int a = eli[p];
    int b = eli[N_LABEL + p];
    uint4 ua = *(const uint4*)(enc + (size_t)a * 64 + c8 * 8);
    uint4 ub = *(const uint4*)(enc + (size_t)b * 64 + c8 * 8);
    float s = dot8h(ua, ub);
    s += __shfl_xor(s, 1, 8);
    s += __shfl_xor(s, 2, 8);
    s += __shfl_xor(s, 4, 8);
    if (c8 == 0) out[p] = s;
}

// ---------------- host ----------------

extern "C" void kernel_launch(void* const* d_in, const int* in_sizes, int n_in,
                              void* d_out, int out_size, void* d_ws, size_t ws_size,
                              hipStream_t stream) {
    const float* x   = (const float*)d_in[0];
    const int*   ei  = (const int*)d_in[1];
    const float* ew  = (const float*)d_in[2];
    const int*   eli = (const int*)d_in[3];
    const float* W[6] = {(const float*)d_in[4],  (const float*)d_in[6],
                         (const float*)d_in[8],  (const float*)d_in[10],
                         (const float*)d_in[12], (const float*)d_in[14]};
    const float* B[6] = {(const float*)d_in[5],  (const float*)d_in[7],
                         (const float*)d_in[9],  (const float*)d_in[11],
                         (const float*)d_in[13], (const float*)d_in[15]};

    char* ws = (char*)d_ws;
    float*  dinv    = (float*)ws;   ws += N_NODES * 4;
    int*    cnt     = (int*)ws;     ws += N_NODES * 4;
    int*    offs    = (int*)ws;     ws += (N_NODES + 16) * 4;
    int*    cursor  = (int*)ws;     ws += N_NODES * 4;
    int*    blksum  = (int*)ws;     ws += 256 * 4;
    int2*   csr_se  = (int2*)ws;    ws += (size_t)N_EDGES * 8;
    __half* xh      = (__half*)ws;  ws += (size_t)N_NODES * DIM_IN * 2;
    __half* hA      = (__half*)ws;  ws += (size_t)N_NODES * 64 * 2;
    __half* hB      = (__half*)ws;

    const int BS = 256;
    const int gLayer = N_NODES / 4;  // one 64-lane wave per node, 4 per block

    // CSR build + norm
    k_init <<<N_NODES / BS, BS, 0, stream>>>(dinv, cnt);
    k_cnt  <<<N_EDGES / BS, BS, 0, stream>>>(ei, ew, cnt, dinv);
    k_scan1<<<64, BS, 0, stream>>>(cnt, blksum);
    k_scan2<<<1, 64, 0, stream>>>(blksum);
    k_scan3<<<64, BS, 0, stream>>>(cnt, blksum, offs, cursor);
    k_dinv <<<N_NODES / BS, BS, 0, stream>>>(dinv);
    k_fill <<<N_EDGES / BS, BS, 0, stream>>>(ei, ew, dinv, cursor, csr_se);

    // cast x to fp16
    k_cast_x<<<N_NODES * DIM_IN / BS, BS, 0, stream>>>(x, xh);

    // fused layers (fp16 tables, fp32 math)
    k_layer<DIM_IN, true ><<<gLayer, BS, 0, stream>>>(offs, csr_se, xh, dinv, W[0], B[0], hA);
    k_layer<DIM_H,  true ><<<gLayer, BS, 0, stream>>>(offs, csr_se, hA, dinv, W[1], B[1], hB);
    k_layer<DIM_H,  true ><<<gLayer, BS, 0, stream>>>(offs, csr_se, hB, dinv, W[2], B[2], hA);
    k_layer<DIM_H,  true ><<<gLayer, BS, 0, stream>>>(offs, csr_se, hA, dinv, W[3], B[3], hB);
    k_layer<DIM_H,  true ><<<gLayer, BS, 0, stream>>>(offs, csr_se, hB, dinv, W[4], B[4], hA);
    k_layer<DIM_H, false><<<gLayer, BS, 0, stream>>>(offs, csr_se, hA, dinv, W[5], B[5], hB);

    // decode (8 lanes per pair)
    k_decode<<<N_LABEL * 8 / BS, BS, 0, stream>>>(eli, hB, (float*)d_out);
}

// Round 14
// 490.064 us; speedup vs baseline: 5.7052x; 1.5595x over previous
//
#include <hip/hip_runtime.h>
#include <hip/hip_fp16.h>

#define N_NODES 65536
#define N_EDGES 1048576
#define N_LABEL 2097152
#define DIM_IN 32
#define DIM_H 64

typedef short short8 __attribute__((ext_vector_type(8)));
typedef float floatx4 __attribute__((ext_vector_type(4)));

// ---------------- CSR build + norm precompute ----------------

__global__ void k_init(float* __restrict__ deg, int* __restrict__ cnt) {
    int v = blockIdx.x * blockDim.x + threadIdx.x;
    deg[v] = 1.0f;  // self-loop weight
    cnt[v] = 0;
}

__global__ void k_cnt(const int* __restrict__ ei, const float* __restrict__ w,
                      int* __restrict__ cnt, float* __restrict__ deg) {
    int e = blockIdx.x * blockDim.x + threadIdx.x;
    int d = ei[N_EDGES + e];
    atomicAdd(&cnt[d], 1);
    atomicAdd(&deg[d], w[e]);
}

// hierarchical exclusive scan over cnt[N] (64 blocks x 1024)
__global__ void k_scan1(const int* __restrict__ cnt, int* __restrict__ blksum) {
    int tid = threadIdx.x;
    const int4* p = (const int4*)(cnt + blockIdx.x * 1024);
    int4 v = p[tid];
    int s = v.x + v.y + v.z + v.w;
    for (int d = 1; d < 64; d <<= 1) s += __shfl_xor(s, d);
    __shared__ int wsum[4];
    if ((tid & 63) == 0) wsum[tid >> 6] = s;
    __syncthreads();
    if (tid == 0) blksum[blockIdx.x] = wsum[0] + wsum[1] + wsum[2] + wsum[3];
}

__global__ void k_scan2(int* __restrict__ blksum) {
    if (threadIdx.x == 0) {
        int run = 0;
        for (int i = 0; i < 64; ++i) { int t = blksum[i]; blksum[i] = run; run += t; }
    }
}

__global__ void k_scan3(const int* __restrict__ cnt, const int* __restrict__ blksum,
                        int* __restrict__ offs, int* __restrict__ cursor) {
    int tid = threadIdx.x, bid = blockIdx.x;
    const int4* p = (const int4*)(cnt + bid * 1024);
    int4 v = p[tid];
    int s = v.x + v.y + v.z + v.w;
    int lane = tid & 63, wid = tid >> 6;
    int sc = s;
    for (int d = 1; d < 64; d <<= 1) {
        int t = __shfl_up(sc, d);
        if (lane >= d) sc += t;
    }
    __shared__ int wsum[4];
    if (lane == 63) wsum[wid] = sc;
    __syncthreads();
    int base = blksum[bid];
    for (int w2 = 0; w2 < wid; ++w2) base += wsum[w2];
    int ex = base + sc - s;  // exclusive prefix of this thread's 4 entries
    int idx = bid * 1024 + tid * 4;
    int o0 = ex, o1 = o0 + v.x, o2 = o1 + v.y, o3 = o2 + v.z;
    offs[idx] = o0; offs[idx + 1] = o1; offs[idx + 2] = o2; offs[idx + 3] = o3;
    cursor[idx] = o0; cursor[idx + 1] = o1; cursor[idx + 2] = o2; cursor[idx + 3] = o3;
    if (bid == 63 && tid == 255) offs[N_NODES] = o3 + v.w;  // == N_EDGES
}

__global__ void k_dinv(float* __restrict__ deg) {
    int v = blockIdx.x * blockDim.x + threadIdx.x;
    deg[v] = rsqrtf(deg[v]);
}

// packed CSR entry: {src, norm-as-bits}
__global__ void k_fill(const int* __restrict__ ei, const float* __restrict__ w,
                       const float* __restrict__ dinv, int* __restrict__ cursor,
                       int2* __restrict__ csr_se) {
    int e = blockIdx.x * blockDim.x + threadIdx.x;
    int s = ei[e];
    int d = ei[N_EDGES + e];
    int pos = atomicAdd(&cursor[d], 1);
    float nm = dinv[s] * w[e] * dinv[d];
    csr_se[pos] = make_int2(s, __float_as_int(nm));
}

// ---------------- cast x to fp16 ----------------

__global__ void k_cast_x(const float* __restrict__ x, __half* __restrict__ xh) {
    int gid = blockIdx.x * 256 + threadIdx.x;  // N*32 threads
    xh[gid] = __float2half(x[gid]);
}

// ---------------- aggregation only: agg[v] = (A_hat h)[v], fp32 out ----------------
// Round-13 gather structure (8 edge rows per uint4 gather instruction, one
// coalesced metadata round per node, convergent shfls) WITHOUT the shfl-GEMM
// epilogue and W staging -> ~6x fewer LDS-pipe ops per wave.

template <int K>
__global__ void __launch_bounds__(256) k_agg(
        const int* __restrict__ offs, const int2* __restrict__ csr_se,
        const __half* __restrict__ h, const float* __restrict__ dinv,
        float* __restrict__ agg) {
    constexpr int LPE = K / 8;     // lanes per edge row (uint4 each): 4 or 8
    constexpr int EPI = 64 / LPE;  // edges per gather instruction: 16 or 8

    int tid = threadIdx.x;
    int v = blockIdx.x * 4 + (tid >> 6);
    int lane = tid & 63;
    int sub = lane % LPE;          // 16 B chunk of row
    int g   = lane / LPE;          // edge slot

    float a[8] = {0.f, 0.f, 0.f, 0.f, 0.f, 0.f, 0.f, 0.f};

    // self-loop term (edge-slot 0 lanes only; no cross-lane ops inside)
    if (g == 0) {
        float dv = dinv[v];
        float sl = dv * dv;
        uint4 rv = *(const uint4*)(h + (size_t)v * K + sub * 8);
        const __half2* hp = (const __half2*)&rv;
#pragma unroll
        for (int i = 0; i < 4; ++i) {
            float2 f = __half22float2(hp[i]);
            a[2 * i]     += sl * f.x;
            a[2 * i + 1] += sl * f.y;
        }
    }

    int j0 = __builtin_amdgcn_readfirstlane(offs[v]);
    int j1 = __builtin_amdgcn_readfirstlane(offs[v + 1]);

    for (int jm = j0; jm < j1; jm += 64) {
        int mi = jm + lane;
        int2 md = csr_se[mi < j1 ? mi : j1 - 1];   // loop entered => j1 > j0
        if (mi >= j1) md.y = 0;                    // 0.0f norm for padding slots
        int nwin = j1 - jm;
        if (nwin > 64) nwin = 64;
        for (int t = 0; t * EPI < nwin; ++t) {     // wave-uniform trip count
            int we = t * EPI + g;                  // window slot (< 64)
            int src = __shfl(md.x, we);            // all 64 lanes active
            float nm = __int_as_float(__shfl(md.y, we));
            uint4 rv = *(const uint4*)(h + (size_t)src * K + sub * 8);
            const __half2* hp = (const __half2*)&rv;
#pragma unroll
            for (int i = 0; i < 4; ++i) {
                float2 f = __half22float2(hp[i]);
                a[2 * i]     += nm * f.x;
                a[2 * i + 1] += nm * f.y;
            }
        }
    }

    // xor-tree: sum partials across edge slots
#pragma unroll
    for (int st = LPE; st < 64; st <<= 1) {
#pragma unroll
        for (int i = 0; i < 8; ++i) a[i] += __shfl_xor(a[i], st);
    }

    // lanes 0..LPE-1 (g==0) write their 8-float chunk, coalesced
    if (lane < LPE) {
        float* dst = agg + (size_t)v * K + lane * 8;
        *(float4*)(dst)     = make_float4(a[0], a[1], a[2], a[3]);
        *(float4*)(dst + 4) = make_float4(a[4], a[5], a[6], a[7]);
    }
}

// ---------------- dense transform via MFMA: out = relu(agg @ W + b) ----------------
// bf16 hi/lo split of both operands: hi@Whi + hi@Wlo + lo@Whi (drop lo@Wlo,
// ~1.5e-5 rel) -> effectively fp32-accurate. mfma_f32_16x16x32_bf16 layout:
// A: lane&15 = row, k = (lane>>4)*8 + j;  B: lane&15 = col, same k map;
// C/D: col = lane&15, row = (lane>>4)*4 + reg (guide m89-verified). Any
// consistent (lane-group,j)->k bijection cancels between A and B.

__device__ __forceinline__ unsigned short f32_bf16(float f) {
    unsigned u = __float_as_uint(f);
    unsigned r = u + 0x7FFFu + ((u >> 16) & 1u);
    return (unsigned short)(r >> 16);
}
__device__ __forceinline__ float bf16_f32(unsigned short h) {
    return __uint_as_float(((unsigned)h) << 16);
}

template <int KIN, bool RELU>
__global__ void __launch_bounds__(256) k_gemm_mfma(
        const float* __restrict__ agg, const float* __restrict__ W,
        const float* __restrict__ b, __half* __restrict__ out) {
    constexpr int KC = KIN / 32;           // k-chunks of 32
    constexpr int NT = N_NODES / 16;       // 16-row tiles
    __shared__ float Wl[KIN * 64];
    int tid = threadIdx.x;
    for (int i = tid; i < KIN * 64; i += 256) Wl[i] = W[i];
    __syncthreads();

    int lane = tid & 63;
    int l15 = lane & 15, l4 = lane >> 4;

    // B fragments (W), hi/lo, built once per wave
    short8 whi[4][KC], wlo[4][KC];
#pragma unroll
    for (int ct = 0; ct < 4; ++ct)
#pragma unroll
        for (int kc = 0; kc < KC; ++kc)
#pragma unroll
            for (int j = 0; j < 8; ++j) {
                float wv = Wl[(kc * 32 + l4 * 8 + j) * 64 + ct * 16 + l15];
                unsigned short hi = f32_bf16(wv);
                unsigned short lo = f32_bf16(wv - bf16_f32(hi));
                whi[ct][kc][j] = (short)hi;
                wlo[ct][kc][j] = (short)lo;
            }
    float bias[4];
#pragma unroll
    for (int ct = 0; ct < 4; ++ct) bias[ct] = b[ct * 16 + l15];

    int wave_id = blockIdx.x * 4 + (tid >> 6);          // 2048 waves
    for (int tile = wave_id; tile < NT; tile += 2048) {
        int r0 = tile * 16;
        const float* arow = agg + (size_t)(r0 + l15) * KIN + l4 * 8;
        short8 ahi[KC], alo[KC];
#pragma unroll
        for (int kc = 0; kc < KC; ++kc) {
            float4 f0 = *(const float4*)(arow + kc * 32);
            float4 f1 = *(const float4*)(arow + kc * 32 + 4);
            float fv[8] = {f0.x, f0.y, f0.z, f0.w, f1.x, f1.y, f1.z, f1.w};
#pragma unroll
            for (int j = 0; j < 8; ++j) {
                unsigned short hi = f32_bf16(fv[j]);
                unsigned short lo = f32_bf16(fv[j] - bf16_f32(hi));
                ahi[kc][j] = (short)hi;
                alo[kc][j] = (short)lo;
            }
        }
        floatx4 acc[4] = {{0.f,0.f,0.f,0.f},{0.f,0.f,0.f,0.f},{0.f,0.f,0.f,0.f},{0.f,0.f,0.f,0.f}};
#pragma unroll
        for (int ct = 0; ct < 4; ++ct)
#pragma unroll
            for (int kc = 0; kc < KC; ++kc) {
                acc[ct] = __builtin_amdgcn_mfma_f32_16x16x32_bf16(ahi[kc], whi[ct][kc], acc[ct], 0, 0, 0);
                acc[ct] = __builtin_amdgcn_mfma_f32_16x16x32_bf16(ahi[kc], wlo[ct][kc], acc[ct], 0, 0, 0);
                acc[ct] = __builtin_amdgcn_mfma_f32_16x16x32_bf16(alo[kc], whi[ct][kc], acc[ct], 0, 0, 0);
            }
#pragma unroll
        for (int ct = 0; ct < 4; ++ct)
#pragma unroll
            for (int r = 0; r < 4; ++r) {
                float o = acc[ct][r] + bias[ct];
                if (RELU) o = fmaxf(o, 0.f);
                out[(size_t)(r0 + l4 * 4 + r) * 64 + ct * 16 + l15] = __float2half(o);
            }
    }
}

// ---------------- decode: out[p] = dot(enc[a], enc[b]); 8 lanes/pair, fp16 rows ----------------

__device__ __forceinline__ float dot8h(uint4 ua, uint4 ub) {
    const __half2* pa = (const __half2*)&ua;
    const __half2* pb = (const __half2*)&ub;
    float s = 0.f;
#pragma unroll
    for (int i = 0; i < 4; ++i) {
        float2 fa = __half22float2(pa[i]);
        float2 fb = __half22float2(pb[i]);
        s += fa.x * fb.x + fa.y * fb.y;
    }
    return s;
}

__global__ void __launch_bounds__(256) k_decode(
        const int* __restrict__ eli, const __half* __restrict__ enc,
        float* __restrict__ out) {
    int gid = blockIdx.x * 256 + threadIdx.x;  // EL*8 threads
    int p = gid >> 3;
    int c8 = gid & 7;  // 8 halves (16 B) per lane
    int a = eli[p];
    int b = eli[N_LABEL + p];
    uint4 ua = *(const uint4*)(enc + (size_t)a * 64 + c8 * 8);
    uint4 ub = *(const uint4*)(enc + (size_t)b * 64 + c8 * 8);
    float s = dot8h(ua, ub);
    s += __shfl_xor(s, 1, 8);
    s += __shfl_xor(s, 2, 8);
    s += __shfl_xor(s, 4, 8);
    if (c8 == 0) out[p] = s;
}

// ---------------- host ----------------

extern "C" void kernel_launch(void* const* d_in, const int* in_sizes, int n_in,
                              void* d_out, int out_size, void* d_ws, size_t ws_size,
                              hipStream_t stream) {
    const float* x   = (const float*)d_in[0];
    const int*   ei  = (const int*)d_in[1];
    const float* ew  = (const float*)d_in[2];
    const int*   eli = (const int*)d_in[3];
    const float* W[6] = {(const float*)d_in[4],  (const float*)d_in[6],
                         (const float*)d_in[8],  (const float*)d_in[10],
                         (const float*)d_in[12], (const float*)d_in[14]};
    const float* B[6] = {(const float*)d_in[5],  (const float*)d_in[7],
                         (const float*)d_in[9],  (const float*)d_in[11],
                         (const float*)d_in[13], (const float*)d_in[15]};

    char* ws = (char*)d_ws;
    float*  dinv    = (float*)ws;   ws += N_NODES * 4;
    int*    cnt     = (int*)ws;     ws += N_NODES * 4;
    int*    offs    = (int*)ws;     ws += (N_NODES + 16) * 4;
    int*    cursor  = (int*)ws;     ws += N_NODES * 4;
    int*    blksum  = (int*)ws;     ws += 256 * 4;
    int2*   csr_se  = (int2*)ws;    ws += (size_t)N_EDGES * 8;
    __half* xh      = (__half*)ws;  ws += (size_t)N_NODES * DIM_IN * 2;
    float*  aggF    = (float*)ws;   ws += (size_t)N_NODES * 64 * 4;  // fp32 agg scratch
    __half* hA      = (__half*)ws;  ws += (size_t)N_NODES * 64 * 2;
    __half* hB      = (__half*)ws;

    const int BS = 256;
    const int gAgg = N_NODES / 4;   // one 64-lane wave per node, 4 per block
    const int gGemm = 512;          // 2048 waves, 2 row-tiles each

    // CSR build + norm
    k_init <<<N_NODES / BS, BS, 0, stream>>>(dinv, cnt);
    k_cnt  <<<N_EDGES / BS, BS, 0, stream>>>(ei, ew, cnt, dinv);
    k_scan1<<<64, BS, 0, stream>>>(cnt, blksum);
    k_scan2<<<1, 64, 0, stream>>>(blksum);
    k_scan3<<<64, BS, 0, stream>>>(cnt, blksum, offs, cursor);
    k_dinv <<<N_NODES / BS, BS, 0, stream>>>(dinv);
    k_fill <<<N_EDGES / BS, BS, 0, stream>>>(ei, ew, dinv, cursor, csr_se);

    // cast x to fp16
    k_cast_x<<<N_NODES * DIM_IN / BS, BS, 0, stream>>>(x, xh);

    // layer 1 (K=32)
    k_agg<DIM_IN><<<gAgg, BS, 0, stream>>>(offs, csr_se, xh, dinv, aggF);
    k_gemm_mfma<DIM_IN, true><<<gGemm, BS, 0, stream>>>(aggF, W[0], B[0], hA);

    // layers 2..5 (K=64)
    k_agg<DIM_H><<<gAgg, BS, 0, stream>>>(offs, csr_se, hA, dinv, aggF);
    k_gemm_mfma<DIM_H, true><<<gGemm, BS, 0, stream>>>(aggF, W[1], B[1], hB);
    k_agg<DIM_H><<<gAgg, BS, 0, stream>>>(offs, csr_se, hB, dinv, aggF);
    k_gemm_mfma<DIM_H, true><<<gGemm, BS, 0, stream>>>(aggF, W[2], B[2], hA);
    k_agg<DIM_H><<<gAgg, BS, 0, stream>>>(offs, csr_se, hA, dinv, aggF);
    k_gemm_mfma<DIM_H, true><<<gGemm, BS, 0, stream>>>(aggF, W[3], B[3], hB);
    k_agg<DIM_H><<<gAgg, BS, 0, stream>>>(offs, csr_se, hB, dinv, aggF);
    k_gemm_mfma<DIM_H, true><<<gGemm, BS, 0, stream>>>(aggF, W[4], B[4], hA);

    // layer 6 (no relu) -> enc
    k_agg<DIM_H><<<gAgg, BS, 0, stream>>>(offs, csr_se, hA, dinv, aggF);
    k_gemm_mfma<DIM_H, false><<<gGemm, BS, 0, stream>>>(aggF, W[5], B[5], hB);

    // decode (8 lanes per pair)
    k_decode<<<N_LABEL * 8 / BS, BS, 0, stream>>>(eli, hB, (float*)d_out);
}

// Round 15
// 413.649 us; speedup vs baseline: 6.7592x; 1.1847x over previous
//
#include <hip/hip_runtime.h>
#include <hip/hip_fp16.h>

#define N_NODES 65536
#define N_EDGES 1048576
#define N_LABEL 2097152
#define DIM_IN 32
#define DIM_H 64

typedef short short8 __attribute__((ext_vector_type(8)));
typedef float floatx4 __attribute__((ext_vector_type(4)));

// ---------------- CSR build + norm precompute ----------------
// packed[v]: high 32 = edge count, low 32 = sum(w) in 2^-24 fixed point.
// ONE 64-bit atomic per edge; its return value = this edge's rank among
// same-dst edges -> k_fill needs no atomics.

__global__ void k_init(unsigned long long* __restrict__ packed) {
    int v = blockIdx.x * blockDim.x + threadIdx.x;
    packed[v] = 0ull;
}

__global__ void k_cnt(const int* __restrict__ ei, const float* __restrict__ w,
                      unsigned long long* __restrict__ packed,
                      unsigned short* __restrict__ rank) {
    int e = blockIdx.x * blockDim.x + threadIdx.x;
    int d = ei[N_EDGES + e];
    unsigned fx = __float2uint_rn(w[e] * 16777216.f);   // w in [0,1)
    unsigned long long old = atomicAdd(&packed[d], (1ull << 32) | (unsigned long long)fx);
    rank[e] = (unsigned short)(old >> 32);
}

// hierarchical exclusive scan over counts (high words) (64 blocks x 1024)
__global__ void k_scan1(const int2* __restrict__ packed, int* __restrict__ blksum) {
    int tid = threadIdx.x;
    const int2* p = packed + blockIdx.x * 1024 + tid * 4;
    int s = p[0].y + p[1].y + p[2].y + p[3].y;
    for (int d = 1; d < 64; d <<= 1) s += __shfl_xor(s, d);
    __shared__ int wsum[4];
    if ((tid & 63) == 0) wsum[tid >> 6] = s;
    __syncthreads();
    if (tid == 0) blksum[blockIdx.x] = wsum[0] + wsum[1] + wsum[2] + wsum[3];
}

__global__ void k_scan2(int* __restrict__ blksum) {
    if (threadIdx.x == 0) {
        int run = 0;
        for (int i = 0; i < 64; ++i) { int t = blksum[i]; blksum[i] = run; run += t; }
    }
}

__global__ void k_scan3(const int2* __restrict__ packed, const int* __restrict__ blksum,
                        int* __restrict__ offs) {
    int tid = threadIdx.x, bid = blockIdx.x;
    const int2* p = packed + bid * 1024 + tid * 4;
    int c0 = p[0].y, c1 = p[1].y, c2 = p[2].y, c3 = p[3].y;
    int s = c0 + c1 + c2 + c3;
    int lane = tid & 63, wid = tid >> 6;
    int sc = s;
    for (int d = 1; d < 64; d <<= 1) {
        int t = __shfl_up(sc, d);
        if (lane >= d) sc += t;
    }
    __shared__ int wsum[4];
    if (lane == 63) wsum[wid] = sc;
    __syncthreads();
    int base = blksum[bid];
    for (int w2 = 0; w2 < wid; ++w2) base += wsum[w2];
    int ex = base + sc - s;  // exclusive prefix of this thread's 4 entries
    int idx = bid * 1024 + tid * 4;
    int o0 = ex, o1 = o0 + c0, o2 = o1 + c1, o3 = o2 + c2;
    offs[idx] = o0; offs[idx + 1] = o1; offs[idx + 2] = o2; offs[idx + 3] = o3;
    if (bid == 63 && tid == 255) offs[N_NODES] = o3 + c3;  // == N_EDGES
}

__global__ void k_dinv(const uint2* __restrict__ packed, float* __restrict__ dinv) {
    int v = blockIdx.x * blockDim.x + threadIdx.x;
    float deg = 1.0f + (float)packed[v].x * (1.f / 16777216.f);  // self-loop + fixed-point sum
    dinv[v] = rsqrtf(deg);
}

// packed CSR entry: {src, norm-as-bits}; position from offs + precomputed rank (no atomics)
__global__ void k_fill(const int* __restrict__ ei, const float* __restrict__ w,
                       const float* __restrict__ dinv, const int* __restrict__ offs,
                       const unsigned short* __restrict__ rank, int2* __restrict__ csr_se) {
    int e = blockIdx.x * blockDim.x + threadIdx.x;
    int s = ei[e];
    int d = ei[N_EDGES + e];
    int pos = offs[d] + rank[e];
    float nm = dinv[s] * w[e] * dinv[d];
    csr_se[pos] = make_int2(s, __float_as_int(nm));
}

// ---------------- cast x to fp16 ----------------

__global__ void k_cast_x(const float* __restrict__ x, __half* __restrict__ xh) {
    int gid = blockIdx.x * 256 + threadIdx.x;  // N*32 threads
    xh[gid] = __float2half(x[gid]);
}

// ---------------- aggregation only: agg[v] = (A_hat h)[v], fp32 out ----------------

template <int K>
__global__ void __launch_bounds__(256) k_agg(
        const int* __restrict__ offs, const int2* __restrict__ csr_se,
        const __half* __restrict__ h, const float* __restrict__ dinv,
        float* __restrict__ agg) {
    constexpr int LPE = K / 8;     // lanes per edge row (uint4 each): 4 or 8
    constexpr int EPI = 64 / LPE;  // edges per gather instruction: 16 or 8

    int tid = threadIdx.x;
    int v = blockIdx.x * 4 + (tid >> 6);
    int lane = tid & 63;
    int sub = lane % LPE;          // 16 B chunk of row
    int g   = lane / LPE;          // edge slot

    float a[8] = {0.f, 0.f, 0.f, 0.f, 0.f, 0.f, 0.f, 0.f};

    // self-loop term (edge-slot 0 lanes only; no cross-lane ops inside)
    if (g == 0) {
        float dv = dinv[v];
        float sl = dv * dv;
        uint4 rv = *(const uint4*)(h + (size_t)v * K + sub * 8);
        const __half2* hp = (const __half2*)&rv;
#pragma unroll
        for (int i = 0; i < 4; ++i) {
            float2 f = __half22float2(hp[i]);
            a[2 * i]     += sl * f.x;
            a[2 * i + 1] += sl * f.y;
        }
    }

    int j0 = __builtin_amdgcn_readfirstlane(offs[v]);
    int j1 = __builtin_amdgcn_readfirstlane(offs[v + 1]);

    for (int jm = j0; jm < j1; jm += 64) {
        int mi = jm + lane;
        int2 md = csr_se[mi < j1 ? mi : j1 - 1];   // loop entered => j1 > j0
        if (mi >= j1) md.y = 0;                    // 0.0f norm for padding slots
        int nwin = j1 - jm;
        if (nwin > 64) nwin = 64;
        for (int t = 0; t * EPI < nwin; ++t) {     // wave-uniform trip count
            int we = t * EPI + g;                  // window slot (< 64)
            int src = __shfl(md.x, we);            // all 64 lanes active
            float nm = __int_as_float(__shfl(md.y, we));
            uint4 rv = *(const uint4*)(h + (size_t)src * K + sub * 8);
            const __half2* hp = (const __half2*)&rv;
#pragma unroll
            for (int i = 0; i < 4; ++i) {
                float2 f = __half22float2(hp[i]);
                a[2 * i]     += nm * f.x;
                a[2 * i + 1] += nm * f.y;
            }
        }
    }

    // xor-tree: sum partials across edge slots
#pragma unroll
    for (int st = LPE; st < 64; st <<= 1) {
#pragma unroll
        for (int i = 0; i < 8; ++i) a[i] += __shfl_xor(a[i], st);
    }

    // lanes 0..LPE-1 (g==0) write their 8-float chunk, coalesced
    if (lane < LPE) {
        float* dst = agg + (size_t)v * K + lane * 8;
        *(float4*)(dst)     = make_float4(a[0], a[1], a[2], a[3]);
        *(float4*)(dst + 4) = make_float4(a[4], a[5], a[6], a[7]);
    }
}

// ---------------- dense transform via MFMA: out = relu(agg @ W + b) ----------------
// bf16 hi/lo split: hi@Whi + hi@Wlo + lo@Whi (drop lo@Wlo) -> fp32-accurate.

__device__ __forceinline__ unsigned short f32_bf16(float f) {
    unsigned u = __float_as_uint(f);
    unsigned r = u + 0x7FFFu + ((u >> 16) & 1u);
    return (unsigned short)(r >> 16);
}
__device__ __forceinline__ float bf16_f32(unsigned short h) {
    return __uint_as_float(((unsigned)h) << 16);
}

template <int KIN, bool RELU>
__global__ void __launch_bounds__(256) k_gemm_mfma(
        const float* __restrict__ agg, const float* __restrict__ W,
        const float* __restrict__ b, __half* __restrict__ out) {
    constexpr int KC = KIN / 32;           // k-chunks of 32
    constexpr int NT = N_NODES / 16;       // 16-row tiles
    __shared__ float Wl[KIN * 64];
    int tid = threadIdx.x;
    for (int i = tid; i < KIN * 64; i += 256) Wl[i] = W[i];
    __syncthreads();

    int lane = tid & 63;
    int l15 = lane & 15, l4 = lane >> 4;

    // B fragments (W), hi/lo, built once per wave
    short8 whi[4][KC], wlo[4][KC];
#pragma unroll
    for (int ct = 0; ct < 4; ++ct)
#pragma unroll
        for (int kc = 0; kc < KC; ++kc)
#pragma unroll
            for (int j = 0; j < 8; ++j) {
                float wv = Wl[(kc * 32 + l4 * 8 + j) * 64 + ct * 16 + l15];
                unsigned short hi = f32_bf16(wv);
                unsigned short lo = f32_bf16(wv - bf16_f32(hi));
                whi[ct][kc][j] = (short)hi;
                wlo[ct][kc][j] = (short)lo;
            }
    float bias[4];
#pragma unroll
    for (int ct = 0; ct < 4; ++ct) bias[ct] = b[ct * 16 + l15];

    int wave_id = blockIdx.x * 4 + (tid >> 6);          // 2048 waves
    for (int tile = wave_id; tile < NT; tile += 2048) {
        int r0 = tile * 16;
        const float* arow = agg + (size_t)(r0 + l15) * KIN + l4 * 8;
        short8 ahi[KC], alo[KC];
#pragma unroll
        for (int kc = 0; kc < KC; ++kc) {
            float4 f0 = *(const float4*)(arow + kc * 32);
            float4 f1 = *(const float4*)(arow + kc * 32 + 4);
            float fv[8] = {f0.x, f0.y, f0.z, f0.w, f1.x, f1.y, f1.z, f1.w};
#pragma unroll
            for (int j = 0; j < 8; ++j) {
                unsigned short hi = f32_bf16(fv[j]);
                unsigned short lo = f32_bf16(fv[j] - bf16_f32(hi));
                ahi[kc][j] = (short)hi;
                alo[kc][j] = (short)lo;
            }
        }
        floatx4 acc[4] = {{0.f,0.f,0.f,0.f},{0.f,0.f,0.f,0.f},{0.f,0.f,0.f,0.f},{0.f,0.f,0.f,0.f}};
#pragma unroll
        for (int ct = 0; ct < 4; ++ct)
#pragma unroll
            for (int kc = 0; kc < KC; ++kc) {
                acc[ct] = __builtin_amdgcn_mfma_f32_16x16x32_bf16(ahi[kc], whi[ct][kc], acc[ct], 0, 0, 0);
                acc[ct] = __builtin_amdgcn_mfma_f32_16x16x32_bf16(ahi[kc], wlo[ct][kc], acc[ct], 0, 0, 0);
                acc[ct] = __builtin_amdgcn_mfma_f32_16x16x32_bf16(alo[kc], whi[ct][kc], acc[ct], 0, 0, 0);
            }
#pragma unroll
        for (int ct = 0; ct < 4; ++ct)
#pragma unroll
            for (int r = 0; r < 4; ++r) {
                float o = acc[ct][r] + bias[ct];
                if (RELU) o = fmaxf(o, 0.f);
                out[(size_t)(r0 + l4 * 4 + r) * 64 + ct * 16 + l15] = __float2half(o);
            }
    }
}

// ---------------- decode: out[p] = dot(enc[a], enc[b]); 8 lanes/pair, fp16 rows ----------------

__device__ __forceinline__ float dot8h(uint4 ua, uint4 ub) {
    const __half2* pa = (const __half2*)&ua;
    const __half2* pb = (const __half2*)&ub;
    float s = 0.f;
#pragma unroll
    for (int i = 0; i < 4; ++i) {
        float2 fa = __half22float2(pa[i]);
        float2 fb = __half22float2(pb[i]);
        s += fa.x * fb.x + fa.y * fb.y;
    }
    return s;
}

__global__ void __launch_bounds__(256) k_decode(
        const int* __restrict__ eli, const __half* __restrict__ enc,
        float* __restrict__ out) {
    int gid = blockIdx.x * 256 + threadIdx.x;  // EL*8 threads
    int p = gid >> 3;
    int c8 = gid & 7;  // 8 halves (16 B) per lane
    int a = eli[p];
    int b = eli[N_LABEL + p];
    uint4 ua = *(const uint4*)(enc + (size_t)a * 64 + c8 * 8);
    uint4 ub = *(const uint4*)(enc + (size_t)b * 64 + c8 * 8);
    float s = dot8h(ua, ub);
    s += __shfl_xor(s, 1, 8);
    s += __shfl_xor(s, 2, 8);
    s += __shfl_xor(s, 4, 8);
    if (c8 == 0) out[p] = s;
}

// ---------------- host ----------------

extern "C" void kernel_launch(void* const* d_in, const int* in_sizes, int n_in,
                              void* d_out, int out_size, void* d_ws, size_t ws_size,
                              hipStream_t stream) {
    const float* x   = (const float*)d_in[0];
    const int*   ei  = (const int*)d_in[1];
    const float* ew  = (const float*)d_in[2];
    const int*   eli = (const int*)d_in[3];
    const float* W[6] = {(const float*)d_in[4],  (const float*)d_in[6],
                         (const float*)d_in[8],  (const float*)d_in[10],
                         (const float*)d_in[12], (const float*)d_in[14]};
    const float* B[6] = {(const float*)d_in[5],  (const float*)d_in[7],
                         (const float*)d_in[9],  (const float*)d_in[11],
                         (const float*)d_in[13], (const float*)d_in[15]};

    char* ws = (char*)d_ws;
    unsigned long long* packed = (unsigned long long*)ws;  ws += (size_t)N_NODES * 8;
    float*          dinv    = (float*)ws;           ws += N_NODES * 4;
    int*            offs    = (int*)ws;             ws += (N_NODES + 16) * 4;
    int*            blksum  = (int*)ws;             ws += 256 * 4;
    unsigned short* rank    = (unsigned short*)ws;  ws += (size_t)N_EDGES * 2;
    int2*           csr_se  = (int2*)ws;            ws += (size_t)N_EDGES * 8;
    __half*         xh      = (__half*)ws;          ws += (size_t)N_NODES * DIM_IN * 2;
    float*          aggF    = (float*)ws;           ws += (size_t)N_NODES * 64 * 4;
    __half*         hA      = (__half*)ws;          ws += (size_t)N_NODES * 64 * 2;
    __half*         hB      = (__half*)ws;

    const int BS = 256;
    const int gAgg = N_NODES / 4;   // one 64-lane wave per node, 4 per block
    const int gGemm = 512;          // 2048 waves, 2 row-tiles each

    // CSR build + norm (one atomic per edge, rank-based fill)
    k_init <<<N_NODES / BS, BS, 0, stream>>>(packed);
    k_cnt  <<<N_EDGES / BS, BS, 0, stream>>>(ei, ew, packed, rank);
    k_scan1<<<64, BS, 0, stream>>>((const int2*)packed, blksum);
    k_scan2<<<1, 64, 0, stream>>>(blksum);
    k_scan3<<<64, BS, 0, stream>>>((const int2*)packed, blksum, offs);
    k_dinv <<<N_NODES / BS, BS, 0, stream>>>((const uint2*)packed, dinv);
    k_fill <<<N_EDGES / BS, BS, 0, stream>>>(ei, ew, dinv, offs, rank, csr_se);

    // cast x to fp16
    k_cast_x<<<N_NODES * DIM_IN / BS, BS, 0, stream>>>(x, xh);

    // layer 1 (K=32)
    k_agg<DIM_IN><<<gAgg, BS, 0, stream>>>(offs, csr_se, xh, dinv, aggF);
    k_gemm_mfma<DIM_IN, true><<<gGemm, BS, 0, stream>>>(aggF, W[0], B[0], hA);

    // layers 2..5 (K=64)
    k_agg<DIM_H><<<gAgg, BS, 0, stream>>>(offs, csr_se, hA, dinv, aggF);
    k_gemm_mfma<DIM_H, true><<<gGemm, BS, 0, stream>>>(aggF, W[1], B[1], hB);
    k_agg<DIM_H><<<gAgg, BS, 0, stream>>>(offs, csr_se, hB, dinv, aggF);
    k_gemm_mfma<DIM_H, true><<<gGemm, BS, 0, stream>>>(aggF, W[2], B[2], hA);
    k_agg<DIM_H><<<gAgg, BS, 0, stream>>>(offs, csr_se, hA, dinv, aggF);
    k_gemm_mfma<DIM_H, true><<<gGemm, BS, 0, stream>>>(aggF, W[3], B[3], hB);
    k_agg<DIM_H><<<gAgg, BS, 0, stream>>>(offs, csr_se, hB, dinv, aggF);
    k_gemm_mfma<DIM_H, true><<<gGemm, BS, 0, stream>>>(aggF, W[4], B[4], hA);

    // layer 6 (no relu) -> enc
    k_agg<DIM_H><<<gAgg, BS, 0, stream>>>(offs, csr_se, hA, dinv, aggF);
    k_gemm_mfma<DIM_H, false><<<gGemm, BS, 0, stream>>>(aggF, W[5], B[5], hB);

    // decode (8 lanes per pair)
    k_decode<<<N_LABEL * 8 / BS, BS, 0, stream>>>(eli, hB, (float*)d_out);
}